// Round 1
// baseline (533.139 us; speedup 1.0000x reference)
//
#include <hip/hip_runtime.h>
#include <math.h>

#define BB 4
#define VV 256
#define HH 128
#define NBI (BB*VV)      // 1024 (b,i) rows
#define NE  (NBI*VV)     // 262144 e-rows
#define BN_EPS 1e-5f

__device__ __forceinline__ float sigmoidf_(float v) {
    return 1.0f / (1.0f + __expf(-v));
}

// ---------------------------------------------------------------------------
// K1: Uh/Vh/Ah/Bh = h @ W^T + b  (4 small GEMVs per row), plus Cw transpose
// grid NBI blocks x 128 threads
// ---------------------------------------------------------------------------
__global__ __launch_bounds__(128)
void k1_lin4(const float* __restrict__ h,
             const float* __restrict__ Uw, const float* __restrict__ Ub,
             const float* __restrict__ Vw, const float* __restrict__ Vb,
             const float* __restrict__ Aw, const float* __restrict__ Ab,
             const float* __restrict__ Bw, const float* __restrict__ Bb,
             const float* __restrict__ Cw,
             float* __restrict__ Uh, float* __restrict__ Vh,
             float* __restrict__ Ah, float* __restrict__ Bh,
             float* __restrict__ cwt)   // [k][h] transpose of Cw
{
    __shared__ float sh[HH];
    int bi = blockIdx.x;
    int o  = threadIdx.x;

    // piggyback: transpose Cw into ws (cwt[k*128+h] = Cw[h*128+k])
    if (bi < HH) cwt[bi*HH + o] = Cw[o*HH + bi];

    sh[o] = h[bi*HH + o];
    __syncthreads();

    float su = Ub[o], sv = Vb[o], sa = Ab[o], sb = Bb[o];
    const float4* sh4 = (const float4*)sh;
    const float4* Uw4 = (const float4*)Uw;
    const float4* Vw4 = (const float4*)Vw;
    const float4* Aw4 = (const float4*)Aw;
    const float4* Bw4 = (const float4*)Bw;
    #pragma unroll 8
    for (int k4 = 0; k4 < 32; ++k4) {
        float4 hv = sh4[k4];
        float4 wu = Uw4[o*32 + k4];
        float4 wv = Vw4[o*32 + k4];
        float4 wa = Aw4[o*32 + k4];
        float4 wb = Bw4[o*32 + k4];
        su += hv.x*wu.x + hv.y*wu.y + hv.z*wu.z + hv.w*wu.w;
        sv += hv.x*wv.x + hv.y*wv.y + hv.z*wv.z + hv.w*wv.w;
        sa += hv.x*wa.x + hv.y*wa.y + hv.z*wa.z + hv.w*wa.w;
        sb += hv.x*wb.x + hv.y*wb.y + hv.z*wb.z + hv.w*wb.w;
    }
    Uh[bi*HH + o] = su;
    Vh[bi*HH + o] = sv;
    Ah[bi*HH + o] = sa;
    Bh[bi*HH + o] = sb;
}

// ---------------------------------------------------------------------------
// K2: main fused pass. One block per (b,i). 256 threads = 8 tj x 32 th.
// Each thread: 2 j-rows x 4 h-channels.
// Computes e_new (-> out1 region), BN partial stats, h_new accumulator,
// x-update accumulator.
// LDS: CwT 64KB + e-tile 8KB + reduce 4KB = 76KB -> 2 blocks/CU
// ---------------------------------------------------------------------------
__global__ __launch_bounds__(256, 2)
void k2_main(const float* __restrict__ e,
             const float* __restrict__ x,
             const int*   __restrict__ graph,
             const float* __restrict__ cwt,     // Cw^T [k][h] from ws
             const float* __restrict__ Cb,
             const float* __restrict__ dw, const float* __restrict__ db,
             const float* __restrict__ ew, const float* __restrict__ ebp,
             const float* __restrict__ Uh, const float* __restrict__ Vh,
             const float* __restrict__ Ah, const float* __restrict__ Bh,
             float* __restrict__ e_new,         // out1 region (stash)
             float* __restrict__ epart,         // [NBI][2][HH] sum, sumsq
             float* __restrict__ hacc,          // [NBI][HH]
             float* __restrict__ xupd)          // [NBI][2]
{
    __shared__ float s_cwt[HH*HH];   // [k][h]
    __shared__ float s_e[16*HH];     // 16 j-rows
    __shared__ float s_red[8*HH];

    int tid = threadIdx.x;
    int bi  = blockIdx.x;          // b*V + i
    int b   = bi >> 8;
    int th  = tid & 31;            // h-group: h = th*4 .. th*4+3
    int tj  = tid >> 5;            // 0..7 -> j-rows tj*2, tj*2+1 in tile
    int h0  = th * 4;
    int row0 = tj * 2;

    // stage CwT (coalesced copy, conflict-free)
    {
        const float4* src = (const float4*)cwt;
        float4* dst = (float4*)s_cwt;
        #pragma unroll
        for (int it = 0; it < 16; ++it) dst[tid + it*256] = src[tid + it*256];
    }

    float4 bhv = ((const float4*)(Bh + bi*HH))[th];
    float4 dwv = ((const float4*)dw)[th];
    float4 cbv = ((const float4*)Cb)[th];
    float4 dbv = ((const float4*)db)[th];
    float cadd0 = cbv.x + dbv.x, cadd1 = cbv.y + dbv.y;
    float cadd2 = cbv.z + dbv.z, cadd3 = cbv.w + dbv.w;
    float4 ewv = ((const float4*)ew)[th];
    float ebv = ebp[0];
    float xi0 = x[bi*2 + 0], xi1 = x[bi*2 + 1];

    float ss0=0, ss1=0, ss2=0, ss3=0;        // sum(e_new) per channel
    float sq0=0, sq1=0, sq2=0, sq3=0;        // sum(e_new^2)
    float hs0=0, hs1=0, hs2=0, hs3=0;        // sum gate*Vh (masked)
    float xa0=0, xa1=0;                      // x-update partial (lane th==0)

    const float4* se4 = (const float4*)s_e;
    const float4* sw4 = (const float4*)s_cwt;

    for (int jt = 0; jt < VV/16; ++jt) {
        __syncthreads();
        // stage 16 e-rows (2048 floats = 512 float4), coalesced
        const float4* esrc = (const float4*)(e + ((size_t)bi*VV + jt*16)*HH);
        float4* sdst = (float4*)s_e;
        sdst[tid]       = esrc[tid];
        sdst[tid + 256] = esrc[tid + 256];
        __syncthreads();

        float a00=0,a01=0,a02=0,a03=0, a10=0,a11=0,a12=0,a13=0;
        #pragma unroll 8
        for (int k4 = 0; k4 < 32; ++k4) {
            float4 ea = se4[row0*32 + k4];
            float4 eb2 = se4[row0*32 + 32 + k4];
            float4 w0 = sw4[(k4*4+0)*32 + th];
            float4 w1 = sw4[(k4*4+1)*32 + th];
            float4 w2 = sw4[(k4*4+2)*32 + th];
            float4 w3 = sw4[(k4*4+3)*32 + th];
            a00 += ea.x*w0.x + ea.y*w1.x + ea.z*w2.x + ea.w*w3.x;
            a01 += ea.x*w0.y + ea.y*w1.y + ea.z*w2.y + ea.w*w3.y;
            a02 += ea.x*w0.z + ea.y*w1.z + ea.z*w2.z + ea.w*w3.z;
            a03 += ea.x*w0.w + ea.y*w1.w + ea.z*w2.w + ea.w*w3.w;
            a10 += eb2.x*w0.x + eb2.y*w1.x + eb2.z*w2.x + eb2.w*w3.x;
            a11 += eb2.x*w0.y + eb2.y*w1.y + eb2.z*w2.y + eb2.w*w3.y;
            a12 += eb2.x*w0.z + eb2.y*w1.z + eb2.z*w2.z + eb2.w*w3.z;
            a13 += eb2.x*w0.w + eb2.y*w1.w + eb2.z*w2.w + eb2.w*w3.w;
        }

        #pragma unroll
        for (int jj = 0; jj < 2; ++jj) {
            float c0 = jj ? a10 : a00;
            float c1 = jj ? a11 : a01;
            float c2 = jj ? a12 : a02;
            float c3 = jj ? a13 : a03;
            int j = jt*16 + row0 + jj;
            float4 ah = ((const float4*)(Ah + ((size_t)b*VV + j)*HH))[th];
            float xj0 = x[(b*VV + j)*2 + 0], xj1 = x[(b*VV + j)*2 + 1];
            float dx = xi0 - xj0, dy = xi1 - xj1;
            float d2 = dx*dx + dy*dy;
            float dist = (d2 > 0.f) ? sqrtf(d2) : 0.f;

            float en0 = c0 + ah.x + bhv.x + dist*dwv.x + cadd0;
            float en1 = c1 + ah.y + bhv.y + dist*dwv.y + cadd1;
            float en2 = c2 + ah.z + bhv.z + dist*dwv.z + cadd2;
            float en3 = c3 + ah.w + bhv.w + dist*dwv.w + cadd3;

            float4 eo; eo.x=en0; eo.y=en1; eo.z=en2; eo.w=en3;
            ((float4*)(e_new + ((size_t)bi*VV + j)*HH))[th] = eo;

            ss0 += en0; ss1 += en1; ss2 += en2; ss3 += en3;
            sq0 += en0*en0; sq1 += en1*en1; sq2 += en2*en2; sq3 += en3*en3;

            // pa = sigmoid(<e_new, ew> + eb): reduce over 32 th-lanes
            float pap = en0*ewv.x + en1*ewv.y + en2*ewv.z + en3*ewv.w;
            pap += __shfl_down(pap, 16, 32);
            pap += __shfl_down(pap, 8, 32);
            pap += __shfl_down(pap, 4, 32);
            pap += __shfl_down(pap, 2, 32);
            pap += __shfl_down(pap, 1, 32);
            if (th == 0) {
                float pa = sigmoidf_(pap + ebv);
                xa0 += pa * dx;
                xa1 += pa * dy;
            }

            int g = graph[(size_t)bi*VV + j];
            if (g != 1) {
                float4 vh = ((const float4*)(Vh + ((size_t)b*VV + j)*HH))[th];
                hs0 += sigmoidf_(en0) * vh.x;
                hs1 += sigmoidf_(en1) * vh.y;
                hs2 += sigmoidf_(en2) * vh.z;
                hs3 += sigmoidf_(en3) * vh.w;
            }
        }
    }

    // ---- block reductions over the 8 tj groups ----
    __syncthreads();
    s_red[tj*HH+h0]=ss0; s_red[tj*HH+h0+1]=ss1; s_red[tj*HH+h0+2]=ss2; s_red[tj*HH+h0+3]=ss3;
    __syncthreads();
    if (tid < HH) {
        float v = 0;
        #pragma unroll
        for (int t = 0; t < 8; ++t) v += s_red[t*HH + tid];
        epart[(size_t)bi*2*HH + tid] = v;
    }
    __syncthreads();
    s_red[tj*HH+h0]=sq0; s_red[tj*HH+h0+1]=sq1; s_red[tj*HH+h0+2]=sq2; s_red[tj*HH+h0+3]=sq3;
    __syncthreads();
    if (tid < HH) {
        float v = 0;
        #pragma unroll
        for (int t = 0; t < 8; ++t) v += s_red[t*HH + tid];
        epart[(size_t)bi*2*HH + HH + tid] = v;
    }
    __syncthreads();
    s_red[tj*HH+h0]=hs0; s_red[tj*HH+h0+1]=hs1; s_red[tj*HH+h0+2]=hs2; s_red[tj*HH+h0+3]=hs3;
    __syncthreads();
    if (tid < HH) {
        float v = 0;
        #pragma unroll
        for (int t = 0; t < 8; ++t) v += s_red[t*HH + tid];
        hacc[bi*HH + tid] = Uh[bi*HH + tid] + v;
    }
    __syncthreads();
    if (th == 0) { s_red[tj] = xa0; s_red[8 + tj] = xa1; }
    __syncthreads();
    if (tid == 0) {
        float sx = 0, sy = 0;
        #pragma unroll
        for (int t = 0; t < 8; ++t) { sx += s_red[t]; sy += s_red[8 + t]; }
        xupd[bi*2 + 0] = sx;
        xupd[bi*2 + 1] = sy;
    }
}

// ---------------------------------------------------------------------------
// K3: finalize BN stats -> per-channel scale/shift for e and h
// blocks 0..127: e-channels (reduce 1024 partials); 128..255: h-channels
// ---------------------------------------------------------------------------
__global__ __launch_bounds__(256)
void k3_stats(const float* __restrict__ epart, const float* __restrict__ hacc,
              const float* __restrict__ gamma_e, const float* __restrict__ beta_e,
              const float* __restrict__ gamma_h, const float* __restrict__ beta_h,
              float* __restrict__ coefs)  // [0]=scale_e,[128]=shift_e,[256]=scale_h,[384]=shift_h
{
    __shared__ float rs[256], rq[256];
    int c = blockIdx.x, tid = threadIdx.x;
    float s = 0, q = 0;
    if (c < HH) {
        for (int r = tid; r < NBI; r += 256) {
            s += epart[(size_t)r*2*HH + c];
            q += epart[(size_t)r*2*HH + HH + c];
        }
    } else {
        int hh = c - HH;
        for (int r = tid; r < NBI; r += 256) {
            float v = hacc[r*HH + hh];
            s += v; q += v*v;
        }
    }
    rs[tid] = s; rq[tid] = q;
    __syncthreads();
    for (int off = 128; off > 0; off >>= 1) {
        if (tid < off) { rs[tid] += rs[tid+off]; rq[tid] += rq[tid+off]; }
        __syncthreads();
    }
    if (tid == 0) {
        float n = (c < HH) ? (float)NE : (float)NBI;
        float mean = rs[0] / n;
        float var  = rq[0] / n - mean*mean;
        int hh; float g, be;
        if (c < HH) { hh = c;      g = gamma_e[hh]; be = beta_e[hh]; }
        else        { hh = c - HH; g = gamma_h[hh]; be = beta_h[hh]; }
        float scale = g * rsqrtf(var + BN_EPS);
        float shift = be - mean*scale;
        if (c < HH) { coefs[hh]        = scale; coefs[HH + hh]   = shift; }
        else        { coefs[2*HH + hh] = scale; coefs[3*HH + hh] = shift; }
    }
}

// ---------------------------------------------------------------------------
// K3b: out0 = h + relu(bn(h_new));  out2 = x + c*xupd
// ---------------------------------------------------------------------------
__global__ __launch_bounds__(256)
void k3b_hx(const float* __restrict__ h, const float* __restrict__ x,
            const float* __restrict__ hacc, const float* __restrict__ xupd,
            const float* __restrict__ coefs, const float* __restrict__ cp,
            float* __restrict__ out0, float* __restrict__ out2)
{
    int gid = blockIdx.x*256 + threadIdx.x;
    if (gid < NBI*HH) {
        int hh = gid & 127;
        float v = hacc[gid]*coefs[2*HH + hh] + coefs[3*HH + hh];
        out0[gid] = h[gid] + fmaxf(v, 0.f);
    } else {
        int t = gid - NBI*HH;
        if (t < NBI*2) out2[t] = x[t] + cp[0]*xupd[t];
    }
}

// ---------------------------------------------------------------------------
// K4: out1 = e + relu(bn(e_new))   (in-place on out1 which holds e_new)
// ---------------------------------------------------------------------------
__global__ __launch_bounds__(256)
void k4_eout(const float* __restrict__ e, const float* __restrict__ coefs,
             float* __restrict__ out1)
{
    const float4* e4 = (const float4*)e;
    float4* o4 = (float4*)out1;
    const float4* sc4 = (const float4*)coefs;
    const float4* sh4 = (const float4*)(coefs + HH);
    const int total = NE * (HH/4);   // 8388608 float4
    for (int i = blockIdx.x*blockDim.x + threadIdx.x; i < total;
         i += gridDim.x*blockDim.x) {
        int hq = i & 31;
        float4 en = o4[i];
        float4 ev = e4[i];
        float4 sc = sc4[hq], sh = sh4[hq];
        float4 r;
        r.x = ev.x + fmaxf(en.x*sc.x + sh.x, 0.f);
        r.y = ev.y + fmaxf(en.y*sc.y + sh.y, 0.f);
        r.z = ev.z + fmaxf(en.z*sc.z + sh.z, 0.f);
        r.w = ev.w + fmaxf(en.w*sc.w + sh.w, 0.f);
        o4[i] = r;
    }
}

// ---------------------------------------------------------------------------
extern "C" void kernel_launch(void* const* d_in, const int* in_sizes, int n_in,
                              void* d_out, int out_size, void* d_ws, size_t ws_size,
                              hipStream_t stream)
{
    (void)in_sizes; (void)n_in; (void)out_size; (void)ws_size;
    const float* h     = (const float*)d_in[0];
    const float* e     = (const float*)d_in[1];
    const float* x     = (const float*)d_in[2];
    const int*   graph = (const int*)d_in[3];
    const float* Uw = (const float*)d_in[4];
    const float* Ub = (const float*)d_in[5];
    const float* Vw = (const float*)d_in[6];
    const float* Vb = (const float*)d_in[7];
    const float* Aw = (const float*)d_in[8];
    const float* Ab = (const float*)d_in[9];
    const float* Bw = (const float*)d_in[10];
    const float* Bbv = (const float*)d_in[11];
    const float* Cw = (const float*)d_in[12];
    const float* Cb = (const float*)d_in[13];
    const float* dw = (const float*)d_in[14];
    const float* db = (const float*)d_in[15];
    const float* ew = (const float*)d_in[16];
    const float* eb = (const float*)d_in[17];
    const float* c  = (const float*)d_in[18];
    const float* gamma_h = (const float*)d_in[19];
    const float* beta_h  = (const float*)d_in[20];
    const float* gamma_e = (const float*)d_in[21];
    const float* beta_e  = (const float*)d_in[22];

    float* out0 = (float*)d_out;
    float* out1 = out0 + NBI*HH;
    float* out2 = out1 + (size_t)NE*HH;

    float* ws    = (float*)d_ws;
    float* Uh    = ws;                      // 131072
    float* Vh    = Uh + NBI*HH;             // 131072
    float* Ah    = Vh + NBI*HH;             // 131072
    float* Bh    = Ah + NBI*HH;             // 131072
    float* hacc  = Bh + NBI*HH;             // 131072
    float* epart = hacc + NBI*HH;           // 262144
    float* xupd  = epart + (size_t)NBI*2*HH;// 2048
    float* coefs = xupd + NBI*2;            // 512
    float* cwt   = coefs + 4*HH;            // 16384   (total ~3.7 MB)

    k1_lin4<<<NBI, 128, 0, stream>>>(h, Uw, Ub, Vw, Vb, Aw, Ab, Bw, Bbv, Cw,
                                     Uh, Vh, Ah, Bh, cwt);
    k2_main<<<NBI, 256, 0, stream>>>(e, x, graph, cwt, Cb, dw, db, ew, eb,
                                     Uh, Vh, Ah, Bh, out1, epart, hacc, xupd);
    k3_stats<<<2*HH, 256, 0, stream>>>(epart, hacc, gamma_e, beta_e,
                                       gamma_h, beta_h, coefs);
    k3b_hx<<<(NBI*HH + NBI*2 + 255)/256, 256, 0, stream>>>(h, x, hacc, xupd,
                                                           coefs, c, out0, out2);
    k4_eout<<<4096, 256, 0, stream>>>(e, coefs, out1);
}

// Round 2
// 463.944 us; speedup vs baseline: 1.1491x; 1.1491x over previous
//
#include <hip/hip_runtime.h>
#include <math.h>

#define BB 4
#define VV 256
#define HH 128
#define NBI (BB*VV)      // 1024 (b,i) rows
#define NE  (NBI*VV)     // 262144 e-rows
#define BN_EPS 1e-5f

typedef short  short8  __attribute__((ext_vector_type(8)));
typedef float  floatx4 __attribute__((ext_vector_type(4)));

__device__ __forceinline__ float sigmoidf_(float v) {
    return 1.0f / (1.0f + __expf(-v));
}

__device__ __forceinline__ unsigned f2bf(float f) {
    union { float f; unsigned u; } c; c.f = f;
    unsigned u = c.u;
    return (u + 0x7fffu + ((u >> 16) & 1u)) >> 16;   // RNE
}

// ---------------------------------------------------------------------------
// K1: Uh/Vh/Ah/Bh = h @ W^T + b  (4 small GEMVs per row), plus Cw -> MFMA
// B-fragment packing (bf16) into ws.
// Packing layout: idx = ((ks*8 + ht)*64 + lane)*8 + j  holds
//   Cw[h][k] with h = ht*16 + (lane&15), k = ks*32 + (lane>>4)*8 + j
// so K2's B-frag is a single contiguous 16B ds_read per lane.
// ---------------------------------------------------------------------------
__global__ __launch_bounds__(128)
void k1_lin4(const float* __restrict__ h,
             const float* __restrict__ Uw, const float* __restrict__ Ub,
             const float* __restrict__ Vw, const float* __restrict__ Vb,
             const float* __restrict__ Aw, const float* __restrict__ Ab,
             const float* __restrict__ Bw, const float* __restrict__ Bb,
             const float* __restrict__ Cw,
             float* __restrict__ Uh, float* __restrict__ Vh,
             float* __restrict__ Ah, float* __restrict__ Bh,
             unsigned short* __restrict__ cwp)
{
    __shared__ float sh[HH];
    int bi = blockIdx.x;
    int o  = threadIdx.x;

    // piggyback: pack Cw into MFMA B-frag bf16 layout (16384 elems total)
    if (bi < 128) {
        int idx  = bi*128 + o;
        int j    = idx & 7;
        int slot = idx >> 3;
        int lane = slot & 63;
        int tile = slot >> 6;       // ks*8 + ht
        int ht   = tile & 7;
        int ks   = tile >> 3;
        int k    = ks*32 + (lane >> 4)*8 + j;
        int hh   = ht*16 + (lane & 15);
        cwp[idx] = (unsigned short)f2bf(Cw[hh*HH + k]);
    }

    sh[o] = h[bi*HH + o];
    __syncthreads();

    float su = Ub[o], sv = Vb[o], sa = Ab[o], sb = Bb[o];
    const float4* sh4 = (const float4*)sh;
    const float4* Uw4 = (const float4*)Uw;
    const float4* Vw4 = (const float4*)Vw;
    const float4* Aw4 = (const float4*)Aw;
    const float4* Bw4 = (const float4*)Bw;
    #pragma unroll 8
    for (int k4 = 0; k4 < 32; ++k4) {
        float4 hv = sh4[k4];
        float4 wu = Uw4[o*32 + k4];
        float4 wv = Vw4[o*32 + k4];
        float4 wa = Aw4[o*32 + k4];
        float4 wb = Bw4[o*32 + k4];
        su += hv.x*wu.x + hv.y*wu.y + hv.z*wu.z + hv.w*wu.w;
        sv += hv.x*wv.x + hv.y*wv.y + hv.z*wv.z + hv.w*wv.w;
        sa += hv.x*wa.x + hv.y*wa.y + hv.z*wa.z + hv.w*wa.w;
        sb += hv.x*wb.x + hv.y*wb.y + hv.z*wb.z + hv.w*wb.w;
    }
    Uh[bi*HH + o] = su;
    Vh[bi*HH + o] = sv;
    Ah[bi*HH + o] = sa;
    Bh[bi*HH + o] = sb;
}

// ---------------------------------------------------------------------------
// K2: main fused pass, MFMA edition. One block per (b,i). 256 thr = 4 waves.
// Wave w computes j-rows [chunk*128 + w*32, +32) x all 128 h, in 2 chunks.
// GEMM: Ce = e_rows(bf16) x CwT(bf16) via mfma_f32_16x16x32_bf16.
//   A-frag straight from global e (fp32->bf16 cvt in regs), B-frag from LDS.
// C/D layout (verified m89/m91): h = lane&15 (+16*ht), j-row = (lane>>4)*4+reg.
// Epilogue fused: e_new write, BN partials, gated message sum, pa/x-update.
// LDS: 32KB B + ~3KB scratch -> not LDS-BW-bound anymore.
// ---------------------------------------------------------------------------
__global__ __launch_bounds__(256, 2)
void k2_main(const float* __restrict__ e,
             const float* __restrict__ x,
             const int*   __restrict__ graph,
             const unsigned short* __restrict__ cwp,
             const float* __restrict__ Cb,
             const float* __restrict__ dw, const float* __restrict__ db,
             const float* __restrict__ ew, const float* __restrict__ ebp,
             const float* __restrict__ Uh, const float* __restrict__ Vh,
             const float* __restrict__ Ah, const float* __restrict__ Bh,
             float* __restrict__ e_new,         // out1 region (stash)
             float* __restrict__ epart,         // [NBI][2][HH]
             float* __restrict__ hacc,          // [NBI][HH]
             float* __restrict__ xupd)          // [NBI][2]
{
    __shared__ unsigned short s_b[16384];   // 32 KB packed B frags
    __shared__ float s_dist[128], s_dx[128], s_dy[128];
    __shared__ int   s_g[128];
    __shared__ float s_red[4*HH];

    int tid  = threadIdx.x;
    int bi   = blockIdx.x;
    int b    = bi >> 8;
    int lane = tid & 63;
    int w    = tid >> 6;
    int hl   = lane & 15;       // h within 16-wide tile; also A-row selector
    int q    = lane >> 4;       // quad: k-octet for A/B frags, j-subrow for C

    // stage packed B: 32768 B = 2048 int4, 8 per thread, coalesced
    {
        const int4* src = (const int4*)cwp;
        int4* dst = (int4*)s_b;
        #pragma unroll
        for (int it = 0; it < 8; ++it) dst[tid + it*256] = src[tid + it*256];
    }

    // per-lane per-h constants (h = ht*16 + hl)
    float pre[8], dwv[8], ewv[8];
    #pragma unroll
    for (int ht = 0; ht < 8; ++ht) {
        int hh = ht*16 + hl;
        pre[ht] = Bh[bi*HH + hh] + Cb[hh] + db[hh];
        dwv[ht] = dw[hh];
        ewv[ht] = ew[hh];
    }
    float ebv = ebp[0];
    float xi0 = x[bi*2 + 0], xi1 = x[bi*2 + 1];

    float ssum[8] = {0,0,0,0,0,0,0,0};
    float ssq [8] = {0,0,0,0,0,0,0,0};
    float hsum[8] = {0,0,0,0,0,0,0,0};
    float xa0 = 0.f, xa1 = 0.f;

    for (int chunk = 0; chunk < 2; ++chunk) {
        __syncthreads();
        if (tid < 128) {
            int j = chunk*128 + tid;
            float xj0 = x[(b*VV + j)*2 + 0], xj1 = x[(b*VV + j)*2 + 1];
            float dx = xi0 - xj0, dy = xi1 - xj1;
            float d2 = dx*dx + dy*dy;
            s_dx[tid] = dx; s_dy[tid] = dy;
            s_dist[tid] = (d2 > 0.f) ? sqrtf(d2) : 0.f;
            s_g[tid] = graph[(size_t)bi*VV + j];
        }
        __syncthreads();

        floatx4 acc[2][8];
        #pragma unroll
        for (int jt = 0; jt < 2; ++jt)
            #pragma unroll
            for (int ht = 0; ht < 8; ++ht)
                acc[jt][ht] = (floatx4){0.f,0.f,0.f,0.f};

        int j0 = chunk*128 + w*32;
        const float* eA0 = e + ((size_t)bi*VV + j0 + hl)*HH;
        const float* eA1 = eA0 + 16*HH;
        int koff = q*8;

        #pragma unroll
        for (int ks = 0; ks < 4; ++ks) {
            union { short8 s8; unsigned u[4]; } a0, a1;
            {
                const float* p = eA0 + ks*32 + koff;
                float4 u0 = *(const float4*)p;
                float4 u1 = *(const float4*)(p + 4);
                a0.u[0] = f2bf(u0.x) | (f2bf(u0.y) << 16);
                a0.u[1] = f2bf(u0.z) | (f2bf(u0.w) << 16);
                a0.u[2] = f2bf(u1.x) | (f2bf(u1.y) << 16);
                a0.u[3] = f2bf(u1.z) | (f2bf(u1.w) << 16);
            }
            {
                const float* p = eA1 + ks*32 + koff;
                float4 u0 = *(const float4*)p;
                float4 u1 = *(const float4*)(p + 4);
                a1.u[0] = f2bf(u0.x) | (f2bf(u0.y) << 16);
                a1.u[1] = f2bf(u0.z) | (f2bf(u0.w) << 16);
                a1.u[2] = f2bf(u1.x) | (f2bf(u1.y) << 16);
                a1.u[3] = f2bf(u1.z) | (f2bf(u1.w) << 16);
            }
            #pragma unroll
            for (int ht = 0; ht < 8; ++ht) {
                short8 bf = *(const short8*)(s_b + ((size_t)((ks*8 + ht)*64 + lane))*8);
                acc[0][ht] = __builtin_amdgcn_mfma_f32_16x16x32_bf16(a0.s8, bf, acc[0][ht], 0, 0, 0);
                acc[1][ht] = __builtin_amdgcn_mfma_f32_16x16x32_bf16(a1.s8, bf, acc[1][ht], 0, 0, 0);
            }
        }

        // ---- epilogue over this chunk's 32 j-rows (per wave) ----
        #pragma unroll
        for (int jt = 0; jt < 2; ++jt) {
            #pragma unroll
            for (int reg = 0; reg < 4; ++reg) {
                int jl = w*32 + jt*16 + q*4 + reg;
                int j  = chunk*128 + jl;
                float dist = s_dist[jl], dx = s_dx[jl], dy = s_dy[jl];
                int g = s_g[jl];
                const float* ahp = Ah + ((size_t)(b*VV + j))*HH;
                const float* vhp = Vh + ((size_t)(b*VV + j))*HH;
                float* enp = e_new + ((size_t)bi*VV + j)*HH;
                float padot = 0.f;
                #pragma unroll
                for (int ht = 0; ht < 8; ++ht) {
                    int hh = ht*16 + hl;
                    float en = acc[jt][ht][reg] + ahp[hh] + pre[ht] + dist*dwv[ht];
                    enp[hh] = en;
                    ssum[ht] += en;
                    ssq[ht]  += en*en;
                    padot    += en*ewv[ht];
                    if (g != 1) hsum[ht] += sigmoidf_(en) * vhp[hh];
                }
                padot += __shfl_xor(padot, 1);
                padot += __shfl_xor(padot, 2);
                padot += __shfl_xor(padot, 4);
                padot += __shfl_xor(padot, 8);
                if (hl == 0) {
                    float pa = sigmoidf_(padot + ebv);
                    xa0 += pa * dx;
                    xa1 += pa * dy;
                }
            }
        }
    }

    // ---- cross-quad reduce (lanes sharing hl, different j-subrows) ----
    #pragma unroll
    for (int ht = 0; ht < 8; ++ht) {
        ssum[ht] += __shfl_xor(ssum[ht], 16); ssum[ht] += __shfl_xor(ssum[ht], 32);
        ssq[ht]  += __shfl_xor(ssq[ht],  16); ssq[ht]  += __shfl_xor(ssq[ht],  32);
        hsum[ht] += __shfl_xor(hsum[ht], 16); hsum[ht] += __shfl_xor(hsum[ht], 32);
    }

    __syncthreads();
    if (lane < 16) {
        #pragma unroll
        for (int ht = 0; ht < 8; ++ht) s_red[w*HH + ht*16 + lane] = ssum[ht];
    }
    __syncthreads();
    if (tid < HH)
        epart[(size_t)bi*2*HH + tid] =
            s_red[tid] + s_red[HH + tid] + s_red[2*HH + tid] + s_red[3*HH + tid];
    __syncthreads();
    if (lane < 16) {
        #pragma unroll
        for (int ht = 0; ht < 8; ++ht) s_red[w*HH + ht*16 + lane] = ssq[ht];
    }
    __syncthreads();
    if (tid < HH)
        epart[(size_t)bi*2*HH + HH + tid] =
            s_red[tid] + s_red[HH + tid] + s_red[2*HH + tid] + s_red[3*HH + tid];
    __syncthreads();
    if (lane < 16) {
        #pragma unroll
        for (int ht = 0; ht < 8; ++ht) s_red[w*HH + ht*16 + lane] = hsum[ht];
    }
    __syncthreads();
    if (tid < HH)
        hacc[bi*HH + tid] = Uh[bi*HH + tid] +
            s_red[tid] + s_red[HH + tid] + s_red[2*HH + tid] + s_red[3*HH + tid];
    __syncthreads();
    if (hl == 0) { s_red[w*4 + q] = xa0; s_red[16 + w*4 + q] = xa1; }
    __syncthreads();
    if (tid == 0) {
        float sx = 0.f, sy = 0.f;
        #pragma unroll
        for (int t = 0; t < 16; ++t) { sx += s_red[t]; sy += s_red[16 + t]; }
        xupd[bi*2 + 0] = sx;
        xupd[bi*2 + 1] = sy;
    }
}

// ---------------------------------------------------------------------------
// K3: finalize BN stats -> per-channel scale/shift for e and h
// ---------------------------------------------------------------------------
__global__ __launch_bounds__(256)
void k3_stats(const float* __restrict__ epart, const float* __restrict__ hacc,
              const float* __restrict__ gamma_e, const float* __restrict__ beta_e,
              const float* __restrict__ gamma_h, const float* __restrict__ beta_h,
              float* __restrict__ coefs)
{
    __shared__ float rs[256], rq[256];
    int c = blockIdx.x, tid = threadIdx.x;
    float s = 0, q = 0;
    if (c < HH) {
        for (int r = tid; r < NBI; r += 256) {
            s += epart[(size_t)r*2*HH + c];
            q += epart[(size_t)r*2*HH + HH + c];
        }
    } else {
        int hh = c - HH;
        for (int r = tid; r < NBI; r += 256) {
            float v = hacc[r*HH + hh];
            s += v; q += v*v;
        }
    }
    rs[tid] = s; rq[tid] = q;
    __syncthreads();
    for (int off = 128; off > 0; off >>= 1) {
        if (tid < off) { rs[tid] += rs[tid+off]; rq[tid] += rq[tid+off]; }
        __syncthreads();
    }
    if (tid == 0) {
        float n = (c < HH) ? (float)NE : (float)NBI;
        float mean = rs[0] / n;
        float var  = rq[0] / n - mean*mean;
        int hh; float g, be;
        if (c < HH) { hh = c;      g = gamma_e[hh]; be = beta_e[hh]; }
        else        { hh = c - HH; g = gamma_h[hh]; be = beta_h[hh]; }
        float scale = g * rsqrtf(var + BN_EPS);
        float shift = be - mean*scale;
        if (c < HH) { coefs[hh]        = scale; coefs[HH + hh]   = shift; }
        else        { coefs[2*HH + hh] = scale; coefs[3*HH + hh] = shift; }
    }
}

// ---------------------------------------------------------------------------
// K4: out1 = e + relu(bn(e_new)) in-place; also (first threads) h and x outs.
// ---------------------------------------------------------------------------
__global__ __launch_bounds__(256)
void k4_eout(const float* __restrict__ e, const float* __restrict__ coefs,
             const float* __restrict__ h, const float* __restrict__ x,
             const float* __restrict__ hacc, const float* __restrict__ xupd,
             const float* __restrict__ cp,
             float* __restrict__ out0, float* __restrict__ out2,
             float* __restrict__ out1)
{
    int gid = blockIdx.x*256 + threadIdx.x;
    if (gid < NBI*HH) {
        int hh = gid & 127;
        float v = hacc[gid]*coefs[2*HH + hh] + coefs[3*HH + hh];
        out0[gid] = h[gid] + fmaxf(v, 0.f);
        if (gid < NBI*2) out2[gid] = x[gid] + cp[0]*xupd[gid];
    }

    const float4* e4 = (const float4*)e;
    float4* o4 = (float4*)out1;
    const float4* sc4 = (const float4*)coefs;
    const float4* sh4 = (const float4*)(coefs + HH);
    const int total = NE * (HH/4);
    for (int i = gid; i < total; i += gridDim.x*256) {
        int hq = i & 31;
        float4 en = o4[i];
        float4 ev = e4[i];
        float4 sc = sc4[hq], sh = sh4[hq];
        float4 r;
        r.x = ev.x + fmaxf(en.x*sc.x + sh.x, 0.f);
        r.y = ev.y + fmaxf(en.y*sc.y + sh.y, 0.f);
        r.z = ev.z + fmaxf(en.z*sc.z + sh.z, 0.f);
        r.w = ev.w + fmaxf(en.w*sc.w + sh.w, 0.f);
        o4[i] = r;
    }
}

// ---------------------------------------------------------------------------
extern "C" void kernel_launch(void* const* d_in, const int* in_sizes, int n_in,
                              void* d_out, int out_size, void* d_ws, size_t ws_size,
                              hipStream_t stream)
{
    (void)in_sizes; (void)n_in; (void)out_size; (void)ws_size;
    const float* h     = (const float*)d_in[0];
    const float* e     = (const float*)d_in[1];
    const float* x     = (const float*)d_in[2];
    const int*   graph = (const int*)d_in[3];
    const float* Uw = (const float*)d_in[4];
    const float* Ub = (const float*)d_in[5];
    const float* Vw = (const float*)d_in[6];
    const float* Vb = (const float*)d_in[7];
    const float* Aw = (const float*)d_in[8];
    const float* Ab = (const float*)d_in[9];
    const float* Bw = (const float*)d_in[10];
    const float* Bbv = (const float*)d_in[11];
    const float* Cw = (const float*)d_in[12];
    const float* Cb = (const float*)d_in[13];
    const float* dw = (const float*)d_in[14];
    const float* db = (const float*)d_in[15];
    const float* ew = (const float*)d_in[16];
    const float* eb = (const float*)d_in[17];
    const float* c  = (const float*)d_in[18];
    const float* gamma_h = (const float*)d_in[19];
    const float* beta_h  = (const float*)d_in[20];
    const float* gamma_e = (const float*)d_in[21];
    const float* beta_e  = (const float*)d_in[22];

    float* out0 = (float*)d_out;
    float* out1 = out0 + NBI*HH;
    float* out2 = out1 + (size_t)NE*HH;

    float* ws    = (float*)d_ws;
    float* Uh    = ws;                      // 131072 f
    float* Vh    = Uh + NBI*HH;
    float* Ah    = Vh + NBI*HH;
    float* Bh    = Ah + NBI*HH;
    float* hacc  = Bh + NBI*HH;
    float* epart = hacc + NBI*HH;           // 262144 f
    float* xupd  = epart + (size_t)NBI*2*HH;
    float* coefs = xupd + NBI*2;
    unsigned short* cwp = (unsigned short*)(coefs + 4*HH);  // 16384 bf16

    k1_lin4<<<NBI, 128, 0, stream>>>(h, Uw, Ub, Vw, Vb, Aw, Ab, Bw, Bbv, Cw,
                                     Uh, Vh, Ah, Bh, cwp);
    k2_main<<<NBI, 256, 0, stream>>>(e, x, graph, cwp, Cb, dw, db, ew, eb,
                                     Uh, Vh, Ah, Bh, out1, epart, hacc, xupd);
    k3_stats<<<2*HH, 256, 0, stream>>>(epart, hacc, gamma_e, beta_e,
                                       gamma_h, beta_h, coefs);
    k4_eout<<<4096, 256, 0, stream>>>(e, coefs, h, x, hacc, xupd, c,
                                      out0, out2, out1);
}